// Round 5
// baseline (765.466 us; speedup 1.0000x reference)
//
#include <hip/hip_runtime.h>
#include <cstdint>

// GridEncoder forward (torch-ngp semantics), MI355X.
// B = 1048576 points, D=3, L=16 levels, C=2, H=16, per_level_scale=2.0,
// log2_hashmap_size=19, align_corners=False.
//
// Level metadata:
//   res(l)   = 16 << l, scale(l) = res - 1
//   dense levels 0,1,2: offsets 0, 4920, 40864, base = res+1,
//     idx = cx + cy*base + cz*base^2
//   hashed levels 3..15: size 2^19, idx = hash & 0x7FFFF,
//     offset(l) = l*524288 - 1257368
//   primes (1, 2654435761, 805459861)
//
// R8 theory of record:
//  * Gather rides the L2 REQUEST-RATE ceiling (~1 req/cy/channel, 16
//    ch/XCD): R3/R5/R7 all measure 0.8-1.0 req/cy/ch while VALU ~9%,
//    HBM ~18%, occ ~90% are slack. Lever = fewer L2 requests.
//    BRANCHLESS PAIRING: corner c=2j is always in aligned 16 B pair
//    ga>>1 (select half by ga&1), corner c=2j+1 in gb>>1. For even-ix
//    lanes (50%) gb>>1 == ga>>1 -> second load is an L1/MSHR merge and
//    never reaches L2. Uniform 8 x dwordx4, no divergence, avg 6 L2
//    req/pt (vs 8). (R5's -20% requests failed only because both
//    exec-masked paths issued; this version has ONE path.)
//  * XYZ planar inputs are STREAMING per band (no intra-band reuse) ->
//    regular loads polluted table L2s (R7 FETCH +90 MB). Gather reads
//    XYZ nontemporal (no L2 allocate); prep stores regular (spill to
//    MALL for the 16x cross-band reuse).
//  * Transpose is stuck at ~190 us (1.4 TB/s) across 3 structures ->
//    not access shape; ws was nt-stored = bypasses MALL = full-HBM
//    latency reads. Fix: ws stores use `global_store_dwordx2 ... sc1`
//    (bypass L2 -> no table pollution (R6 lesson), but ALLOCATE in the
//    256 MiB memory-side Infinity Cache). Transpose then reads ws at
//    MALL latency/BW. Inter-kernel CP cache fences handle visibility.

namespace {

using f32x2 = __attribute__((ext_vector_type(2))) float;
using f32x4 = __attribute__((ext_vector_type(4))) float;

// Store 8 B bypassing L2 (sc1) but allocating in MALL (no nt bit).
__device__ __forceinline__ void store_sc1_f32x2(f32x2* p, f32x2 v) {
  asm volatile("global_store_dwordx2 %0, %1, off sc1"
               :: "v"(p), "v"(v) : "memory");
}

// Paired corner indices + interp factors for one level.
// ga[j] = global index of corner c=2j (x = ix),  j bit0 = y, bit1 = z
// gb[j] = global index of corner c=2j+1 (x = ix+1)
__device__ __forceinline__ void corner_pairs(
    float x, float y, float z, uint32_t l,
    uint32_t ga[4], uint32_t gb[4], float f[6]) {
  uint32_t res = 16u << l;
  float scale = (float)res - 1.0f;
  float px = x * scale + 0.5f;
  float py = y * scale + 0.5f;
  float pz = z * scale + 0.5f;
  float gx = floorf(px), gy = floorf(py), gz = floorf(pz);
  float rx = px - gx, ry = py - gy, rz = pz - gz;
  uint32_t ix = (uint32_t)gx, iy = (uint32_t)gy, iz = (uint32_t)gz;

  if (l >= 3u) {
    uint32_t off = l * 524288u - 1257368u;
    const uint32_t P2 = 2654435761u, P3 = 805459861u;
    uint32_t hy0 = iy * P2, hy1 = hy0 + P2;
    uint32_t hz0 = iz * P3, hz1 = hz0 + P3;
    uint32_t hb[4] = {hy0 ^ hz0, hy1 ^ hz0, hy0 ^ hz1, hy1 ^ hz1};
    uint32_t ix1 = ix + 1u;
#pragma unroll
    for (int j = 0; j < 4; ++j) {
      ga[j] = ((ix  ^ hb[j]) & 0x7FFFFu) + off;
      gb[j] = ((ix1 ^ hb[j]) & 0x7FFFFu) + off;
    }
  } else {
    uint32_t off = (l == 0u) ? 0u : ((l == 1u) ? 4920u : 40864u);
    uint32_t base = res + 1u;
    uint32_t bb = base * base;
    uint32_t dy0 = iy * base, dy1 = dy0 + base;
    uint32_t dz0 = iz * bb,   dz1 = dz0 + bb;
    uint32_t dyz[4] = {dy0 + dz0, dy1 + dz0, dy0 + dz1, dy1 + dz1};
#pragma unroll
    for (int j = 0; j < 4; ++j) {
      uint32_t d = ix + dyz[j] + off;
      ga[j] = d;
      gb[j] = d + 1u;
    }
  }
  f[0] = 1.0f - rx; f[1] = rx;
  f[2] = 1.0f - ry; f[3] = ry;
  f[4] = 1.0f - rz; f[5] = rz;
}

// Select halves of the loaded pairs and interpolate.
__device__ __forceinline__ f32x2 consume_pairs(
    const f32x4 qa[4], const f32x4 qb[4],
    const uint32_t ga[4], const uint32_t gb[4], const float f[6]) {
  float o0 = 0.0f, o1 = 0.0f;
#pragma unroll
  for (int j = 0; j < 4; ++j) {
    float wyz = f[2 + (j & 1)] * f[4 + ((j >> 1) & 1)];
    bool sa = (ga[j] & 1u) != 0u;
    bool sb = (gb[j] & 1u) != 0u;
    float eax = sa ? qa[j].z : qa[j].x, eay = sa ? qa[j].w : qa[j].y;
    float ebx = sb ? qb[j].z : qb[j].x, eby = sb ? qb[j].w : qb[j].y;
    float wA = f[0] * wyz, wB = f[1] * wyz;
    o0 = fmaf(wA, eax, fmaf(wB, ebx, o0));
    o1 = fmaf(wA, eay, fmaf(wB, eby, o1));
  }
  f32x2 r; r.x = o0; r.y = o1;
  return r;
}

// ---- Pass 0: normalize inputs into planar X,Y,Z (12 MiB, MALL-hot) ----
__global__ __launch_bounds__(256) void prep_xyz_kernel(
    const float* __restrict__ in,    // [B,3] in [-1,1]
    float* __restrict__ X, float* __restrict__ Y, float* __restrict__ Z,
    uint32_t B) {
  uint32_t t = blockIdx.x * 256u + threadIdx.x;
  uint32_t nquad = B >> 2;          // B % 4 == 0 guaranteed by launcher
  if (t >= nquad) return;
  const f32x4* in4 = reinterpret_cast<const f32x4*>(in);
  f32x4 q0 = __builtin_nontemporal_load(&in4[t * 3 + 0]);
  f32x4 q1 = __builtin_nontemporal_load(&in4[t * 3 + 1]);
  f32x4 q2 = __builtin_nontemporal_load(&in4[t * 3 + 2]);
  f32x4 xv = {q0.x, q0.w, q1.z, q2.y};
  f32x4 yv = {q0.y, q1.x, q1.w, q2.z};
  f32x4 zv = {q0.z, q1.y, q2.x, q2.w};
  xv = (xv + 1.0f) * 0.5f;
  yv = (yv + 1.0f) * 0.5f;
  zv = (zv + 1.0f) * 0.5f;
  reinterpret_cast<f32x4*>(X)[t] = xv;   // regular: lands in L2 -> MALL
  reinterpret_cast<f32x4*>(Y)[t] = yv;
  reinterpret_cast<f32x4*>(Z)[t] = zv;
}

// ---- Pass 1: level-phased gather, 2 pts/thread, paired 16 B loads ----
template <bool XYZ>
__global__ __launch_bounds__(256, 5) void gather_lm_kernel(
    const float* __restrict__ in,
    const float* __restrict__ X, const float* __restrict__ Y,
    const float* __restrict__ Z,
    const f32x2* __restrict__ emb,     // [7131240] float2
    f32x2* __restrict__ ws,            // [16*B] float2, level-major
    uint32_t B) {
  uint32_t l = blockIdx.y;
  uint32_t p0 = blockIdx.x * 512u + threadIdx.x;
  uint32_t p1 = p0 + 256u;
  bool vA = p0 < B, vB = p1 < B;
  if (!vA) return;
  uint32_t p1c = vB ? p1 : p0;

  // nontemporal XYZ reads: streaming per band, keep out of table L2
  float xA, yA, zA, xB, yB, zB;
  if (XYZ) {
    xA = __builtin_nontemporal_load(&X[p0]);
    yA = __builtin_nontemporal_load(&Y[p0]);
    zA = __builtin_nontemporal_load(&Z[p0]);
    xB = __builtin_nontemporal_load(&X[p1c]);
    yB = __builtin_nontemporal_load(&Y[p1c]);
    zB = __builtin_nontemporal_load(&Z[p1c]);
  } else {
    xA = (__builtin_nontemporal_load(&in[p0 * 3 + 0]) + 1.0f) * 0.5f;
    yA = (__builtin_nontemporal_load(&in[p0 * 3 + 1]) + 1.0f) * 0.5f;
    zA = (__builtin_nontemporal_load(&in[p0 * 3 + 2]) + 1.0f) * 0.5f;
    xB = (__builtin_nontemporal_load(&in[p1c * 3 + 0]) + 1.0f) * 0.5f;
    yB = (__builtin_nontemporal_load(&in[p1c * 3 + 1]) + 1.0f) * 0.5f;
    zB = (__builtin_nontemporal_load(&in[p1c * 3 + 2]) + 1.0f) * 0.5f;
  }

  const f32x4* __restrict__ pr = reinterpret_cast<const f32x4*>(emb);

  // --- issue A's 8 paired loads ---
  uint32_t gaA[4], gbA[4]; float fA[6];
  corner_pairs(xA, yA, zA, l, gaA, gbA, fA);
  f32x4 qaA[4], qbA[4];
#pragma unroll
  for (int j = 0; j < 4; ++j) qaA[j] = pr[gaA[j] >> 1];
#pragma unroll
  for (int j = 0; j < 4; ++j) qbA[j] = pr[gbA[j] >> 1];  // L1-merge if ==qaA

  // --- issue B's 8 paired loads (overlap A's latency) ---
  uint32_t gaB[4], gbB[4]; float fB[6];
  corner_pairs(xB, yB, zB, l, gaB, gbB, fB);
  f32x4 qaB[4], qbB[4];
#pragma unroll
  for (int j = 0; j < 4; ++j) qaB[j] = pr[gaB[j] >> 1];
#pragma unroll
  for (int j = 0; j < 4; ++j) qbB[j] = pr[gbB[j] >> 1];

  // --- consume A, then B ---
  f32x2 rA = consume_pairs(qaA, qbA, gaA, gbA, fA);
  store_sc1_f32x2(&ws[(size_t)l * B + p0], rA);
  if (vB) {
    f32x2 rB = consume_pairs(qaB, qbB, gaB, gbB, fB);
    store_sc1_f32x2(&ws[(size_t)l * B + p1], rB);
  }
}

// ---- Pass 2: transpose level-major ws -> point-major out ----
// Two point-pair units per thread (4 loads + 4 stores, ILP). Unit u:
// j = u&7, q0 = 2*(u>>3); loads rows 2j,2j+1 as f32x4 (16 B aligned,
// q0 even); stores points q0,q0+1 as f32x4. Per store instruction each
// lane-octet writes 128 B contiguous. ws loads are regular: ws is
// MALL-resident (sc1 stores), reads come back at L3 latency, not HBM.
__global__ __launch_bounds__(256) void transpose_kernel(
    const f32x2* __restrict__ ws,   // [16*B] level-major
    f32x4* __restrict__ out,        // [B*8] float4 == [B,16,2] floats
    uint32_t B) {
  uint32_t half = B * 2u;           // (B/2 pairs * 8 j) / 2 units
  uint32_t t = blockIdx.x * 256u + threadIdx.x;
  if (t >= half) return;
  const f32x4* ws4 = reinterpret_cast<const f32x4*>(ws);

  uint32_t u0 = t, u1 = t + half;
  uint32_t j0 = u0 & 7u, q00 = (u0 >> 3) * 2u;
  uint32_t j1 = u1 & 7u, q10 = (u1 >> 3) * 2u;

  f32x4 va0 = ws4[((size_t)(2u * j0)      * B + q00) >> 1];
  f32x4 vb0 = ws4[((size_t)(2u * j0 + 1u) * B + q00) >> 1];
  f32x4 va1 = ws4[((size_t)(2u * j1)      * B + q10) >> 1];
  f32x4 vb1 = ws4[((size_t)(2u * j1 + 1u) * B + q10) >> 1];

  f32x4 w00 = {va0.x, va0.y, vb0.x, vb0.y};
  f32x4 w01 = {va0.z, va0.w, vb0.z, vb0.w};
  f32x4 w10 = {va1.x, va1.y, vb1.x, vb1.y};
  f32x4 w11 = {va1.z, va1.w, vb1.z, vb1.w};
  __builtin_nontemporal_store(w00, &out[(size_t)q00 * 8u + j0]);
  __builtin_nontemporal_store(w01, &out[(size_t)(q00 + 1u) * 8u + j0]);
  __builtin_nontemporal_store(w10, &out[(size_t)q10 * 8u + j1]);
  __builtin_nontemporal_store(w11, &out[(size_t)(q10 + 1u) * 8u + j1]);
}

// ---- Fallback (ws too small / B%4 != 0): single-pass kernel ----
__global__ __launch_bounds__(256) void grid_encode_fallback(
    const float* __restrict__ in, const f32x2* __restrict__ emb,
    f32x2* __restrict__ out, uint32_t B) {
  uint32_t p = blockIdx.x * 256u + threadIdx.x;
  if (p >= B) return;
  float x = (in[p * 3 + 0] + 1.0f) * 0.5f;
  float y = (in[p * 3 + 1] + 1.0f) * 0.5f;
  float z = (in[p * 3 + 2] + 1.0f) * 0.5f;
  const f32x4* __restrict__ pr = reinterpret_cast<const f32x4*>(emb);
#pragma unroll 1
  for (uint32_t l = 0; l < 16u; ++l) {
    uint32_t ga[4], gb[4]; float f[6];
    corner_pairs(x, y, z, l, ga, gb, f);
    f32x4 qa[4], qb[4];
#pragma unroll
    for (int j = 0; j < 4; ++j) qa[j] = pr[ga[j] >> 1];
#pragma unroll
    for (int j = 0; j < 4; ++j) qb[j] = pr[gb[j] >> 1];
    out[(size_t)p * 16u + l] = consume_pairs(qa, qb, ga, gb, f);
  }
}

}  // namespace

extern "C" void kernel_launch(void* const* d_in, const int* in_sizes, int n_in,
                              void* d_out, int out_size, void* d_ws, size_t ws_size,
                              hipStream_t stream) {
  (void)n_in; (void)out_size;
  const float* in = (const float*)d_in[0];
  const f32x2* emb = (const f32x2*)d_in[1];
  uint32_t B = (uint32_t)(in_sizes[0] / 3);

  size_t ws_lm   = (size_t)16 * B * sizeof(f32x2);          // 128 MiB at B=1M
  size_t ws_full = ws_lm + (size_t)3 * B * sizeof(float);   // + 12 MiB xyz

  if ((B % 4u) == 0u && ws_size >= ws_lm) {
    f32x2* ws = (f32x2*)d_ws;
    uint32_t gblocks = (B + 511u) / 512u;
    bool use_xyz = ws_size >= ws_full;
    if (use_xyz) {
      float* X = (float*)((char*)d_ws + ws_lm);
      float* Y = X + B;
      float* Z = Y + B;
      uint32_t pblocks = ((B >> 2) + 255u) / 256u;
      hipLaunchKernelGGL(prep_xyz_kernel, dim3(pblocks), dim3(256), 0, stream,
                         in, X, Y, Z, B);
      hipLaunchKernelGGL((gather_lm_kernel<true>), dim3(gblocks, 16), dim3(256),
                         0, stream, in, X, Y, Z, emb, ws, B);
    } else {
      hipLaunchKernelGGL((gather_lm_kernel<false>), dim3(gblocks, 16), dim3(256),
                         0, stream, in, nullptr, nullptr, nullptr, emb, ws, B);
    }
    uint32_t tblocks = (B * 2u + 255u) / 256u;
    hipLaunchKernelGGL(transpose_kernel, dim3(tblocks), dim3(256), 0, stream,
                       ws, (f32x4*)d_out, B);
  } else {
    uint32_t pblocks = (B + 255u) / 256u;
    hipLaunchKernelGGL(grid_encode_fallback, dim3(pblocks), dim3(256), 0,
                       stream, in, emb, (f32x2*)d_out, B);
  }
}